// Round 12
// baseline (78.216 us; speedup 1.0000x reference)
//
#include <hip/hip_runtime.h>
#include <math.h>

// Problem constants (from reference setup_inputs)
#define B   16
#define NH  1024
#define NO  2048
#define DQ  24

#define ALPHA_FOCAL 0.25f
#define MARGIN_PEN  0.005f
#define RADIUS_REP  0.015f
#define R2REP       (RADIUS_REP * RADIUS_REP)

// ws layout (floats, 64 B total — the ONLY global scratch):
//   0,1: hand cd dir0/dir1   2,3: obj cd dir0/dir1 (hc-weighted)
//   4: repulsion shifted sum S = sum min(d,R) incl diag (hc-weighted)
//   5: penetration (hc-weighted)  6: focal  7: qpos  8: pose (hc-weighted)
//   9: valid   15: ticket counter (uint)
#define WS_SCAL 16
#define NW      8          // waves per block (512 threads)

typedef float v2f __attribute__((ext_vector_type(2)));
typedef float v4f __attribute__((ext_vector_type(4)));

__device__ inline float wsqrt(float x) { return __builtin_amdgcn_sqrtf(x); }

__device__ inline float block_reduce_sum(float v, float* red) {
    #pragma unroll
    for (int off = 32; off > 0; off >>= 1) v += __shfl_down(v, off, 64);
    int lane = threadIdx.x & 63;
    int wid  = threadIdx.x >> 6;
    if (lane == 0) red[wid] = v;
    __syncthreads();
    float s = 0.f;
    if (threadIdx.x == 0) {
        #pragma unroll
        for (int i = 0; i < NW; ++i) s += red[i];
    }
    __syncthreads();
    return s;   // valid in thread 0 only
}

// Chamfer/penetration tile: 512 rows (8 contiguous rows/lane = NRP 4 pairs)
// x (NW*NCH*64) cols. 8 waves split cols; each wave stages its 64-col chunk
// into a private LDS region (double-buffered), reads it back uniformly
// (1 ds_read_b128 per col -> 16 pk-VALU instrs: VALU-bound at CU level).
// Per-wave row mins merge in LDS; ONE scalar atomicAdd per call.
template<int NCH, bool PEN>
__device__ __forceinline__ void chamfer_block(
    const float* __restrict__ Pb, const float* __restrict__ Qb,
    int slot, float weight,
    v4f (*qsb)[NW][64], float (*mbuf)[512], float* red, float* ws)
{
    const int tid = threadIdx.x;
    const int w   = tid >> 6;
    const int l   = tid & 63;

    // This lane's 8 contiguous P rows: 24 floats = 6 dwordx4
    v4f f4[6];
    const v4f* pv = (const v4f*)(Pb + l*24);
    #pragma unroll
    for (int i = 0; i < 6; ++i) f4[i] = pv[i];
    const float* f = (const float*)f4;

    v2f px2[4], py2[4], pz2[4], m2[4];
    #pragma unroll
    for (int rp = 0; rp < 4; ++rp) {
        px2[rp] = (v2f){f[6*rp+0], f[6*rp+3]};
        py2[rp] = (v2f){f[6*rp+1], f[6*rp+4]};
        pz2[rp] = (v2f){f[6*rp+2], f[6*rp+5]};
        m2[rp]  = (v2f){1e30f, 1e30f};
    }

    auto cstep = [&](v4f Q) {
        v2f bx = __builtin_shufflevector(Q, Q, 0, 0);
        v2f by = __builtin_shufflevector(Q, Q, 1, 1);
        v2f bz = __builtin_shufflevector(Q, Q, 2, 2);
        v2f bw = __builtin_shufflevector(Q, Q, 3, 3);
        #pragma unroll
        for (int rp = 0; rp < 4; ++rp) {
            v2f t = __builtin_elementwise_fma(bz, pz2[rp], bw);
            t     = __builtin_elementwise_fma(by, py2[rp], t);
            t     = __builtin_elementwise_fma(bx, px2[rp], t);
            m2[rp] = __builtin_elementwise_min(m2[rp], t);
        }
    };

    // wave w owns col chunks [w*NCH, (w+1)*NCH), 64 cols each
    const float* qp0 = Qb + (w*NCH)*192 + l*3;
    float qx = qp0[0], qy = qp0[1], qz = qp0[2];
    int p = 0;
    #pragma unroll 1
    for (int cc = 0; cc < NCH; ++cc) {
        qsb[p][w][l] = (v4f){-2.f*qx, -2.f*qy, -2.f*qz,
                             fmaf(qx, qx, fmaf(qy, qy, qz*qz))};
        if (cc + 1 < NCH) {
            const float* qp = Qb + (w*NCH + cc + 1)*192 + l*3;
            qx = qp[0]; qy = qp[1]; qz = qp[2];
        }
        const v4f* qw_ = qsb[p][w];
        v4f Q0 = qw_[0], Q1 = qw_[1], Q2 = qw_[2], Q3 = qw_[3];
        for (int j = 0; j < 60; j += 4) {
            cstep(Q0); Q0 = qw_[j+4];
            cstep(Q1); Q1 = qw_[j+5];
            cstep(Q2); Q2 = qw_[j+6];
            cstep(Q3); Q3 = qw_[j+7];
        }
        cstep(Q0); cstep(Q1); cstep(Q2); cstep(Q3);
        p ^= 1;
    }

    // per-wave mins (pn folded: exact for min-merge) -> LDS
    #pragma unroll
    for (int rp = 0; rp < 4; ++rp) {
        #pragma unroll
        for (int e = 0; e < 2; ++e) {
            float x = px2[rp][e], y = py2[rp][e], z = pz2[rp][e];
            float pn = fmaf(x, x, fmaf(y, y, z*z));
            mbuf[w][l*8 + 2*rp + e] = m2[rp][e] + pn;
        }
    }
    __syncthreads();

    // 512 threads, 512 rows: one row each; merge 8 waves
    float mv = mbuf[0][tid];
    #pragma unroll
    for (int ww = 1; ww < NW; ++ww) mv = fminf(mv, mbuf[ww][tid]);
    float d = wsqrt(fmaxf(mv, 1e-12f));
    float s = PEN ? fmaxf(MARGIN_PEN - d, 0.f) : d;
    float bs = block_reduce_sum(s, red);
    if (tid == 0) atomicAdd(&ws[slot], bs * weight);
}

// Repulsion tile: 512 rows x 2048 cols; sum of min(d,R) (diag included,
// fixed analytically in finalize). One scalar atomicAdd per block.
__device__ __forceinline__ void rep_block(
    const float* __restrict__ Pb, const float* __restrict__ Qb,
    float weight, v4f (*qsb)[NW][64], float* red, float* ws)
{
    const int tid = threadIdx.x;
    const int w   = tid >> 6;
    const int l   = tid & 63;

    v4f f4[6];
    const v4f* pv = (const v4f*)(Pb + l*24);
    #pragma unroll
    for (int i = 0; i < 6; ++i) f4[i] = pv[i];
    const float* f = (const float*)f4;

    v2f px2[4], py2[4], pz2[4], pn2[4];
    #pragma unroll
    for (int rp = 0; rp < 4; ++rp) {
        px2[rp] = (v2f){f[6*rp+0], f[6*rp+3]};
        py2[rp] = (v2f){f[6*rp+1], f[6*rp+4]};
        pz2[rp] = (v2f){f[6*rp+2], f[6*rp+5]};
        pn2[rp] = __builtin_elementwise_fma(px2[rp], px2[rp],
                  __builtin_elementwise_fma(py2[rp], py2[rp], pz2[rp]*pz2[rp]));
    }

    v2f sacc = (v2f){0.f, 0.f};
    const v2f vR = (v2f){RADIUS_REP, RADIUS_REP};
    auto rstep = [&](v4f Q) {
        v2f bx = __builtin_shufflevector(Q, Q, 0, 0);
        v2f by = __builtin_shufflevector(Q, Q, 1, 1);
        v2f bz = __builtin_shufflevector(Q, Q, 2, 2);
        v2f bw = __builtin_shufflevector(Q, Q, 3, 3);
        #pragma unroll
        for (int rp = 0; rp < 4; ++rp) {
            v2f t = __builtin_elementwise_fma(bz, pz2[rp], bw);
            t     = __builtin_elementwise_fma(by, py2[rp], t);
            t     = __builtin_elementwise_fma(bx, px2[rp], t);
            v2f d2 = t + pn2[rp];
            if (__any(fminf(d2.x, d2.y) < R2REP)) {
                // min(d,R) exactly (diag d2~0 -> ~1e-6, fixed in finalize)
                v2f dd;
                dd.x = wsqrt(__builtin_amdgcn_fmed3f(d2.x, 1e-12f, R2REP));
                dd.y = wsqrt(__builtin_amdgcn_fmed3f(d2.y, 1e-12f, R2REP));
                sacc += dd;
            } else {
                sacc += vR;     // min(d,R) = R for both elements
            }
        }
    };

    const float* qp0 = Qb + (w*4)*192 + l*3;
    float qx = qp0[0], qy = qp0[1], qz = qp0[2];
    int p = 0;
    #pragma unroll 1
    for (int cc = 0; cc < 4; ++cc) {
        qsb[p][w][l] = (v4f){-2.f*qx, -2.f*qy, -2.f*qz,
                             fmaf(qx, qx, fmaf(qy, qy, qz*qz))};
        if (cc + 1 < 4) {
            const float* qp = Qb + (w*4 + cc + 1)*192 + l*3;
            qx = qp[0]; qy = qp[1]; qz = qp[2];
        }
        const v4f* qw_ = qsb[p][w];
        v4f Q0 = qw_[0], Q1 = qw_[1], Q2 = qw_[2], Q3 = qw_[3];
        for (int j = 0; j < 60; j += 4) {
            rstep(Q0); Q0 = qw_[j+4];
            rstep(Q1); Q1 = qw_[j+5];
            rstep(Q2); Q2 = qw_[j+6];
            rstep(Q3); Q3 = qw_[j+7];
        }
        rstep(Q0); rstep(Q1); rstep(Q2); rstep(Q3);
        p ^= 1;
    }

    float bs = block_reduce_sum(sacc.x + sacc.y, red);
    if (tid == 0) atomicAdd(&ws[4], bs * weight);
}

// 259 blocks x 512 threads. Heavy blocks all = 1M cells (uniform, 1/CU):
//  [  0,128): obj cd   dir(2) x b(16) x rs(4): 512 rows x 2048 cols
//  [128,192): repulsion b(16) x rs(4):         512 rows x 2048 cols
//  [192,224): hand cd  dir(2) x b(16): two passes of 512 rows x 1024 cols
//  [224,256): pen      b(16) x half(2): two passes of 512 rows x 1024 cols
//  256 focal, 257 qpos, 258 pose+valid. Ticket: last of 259 finalizes out[0].
__global__ __launch_bounds__(512, 4) void loss_kernel(
    const float* __restrict__ pred_hand, const float* __restrict__ pred_obj,
    const float* __restrict__ gt_hand,   const float* __restrict__ gt_obj,
    const float* __restrict__ has_contact,
    const float* __restrict__ logits,    const float* __restrict__ gt_contact,
    const float* __restrict__ pred_qpos, const float* __restrict__ gt_qpos,
    const float* __restrict__ pred_pose, const float* __restrict__ gt_pose,
    float* __restrict__ ws, float* __restrict__ out)
{
    __shared__ v4f   qsb[2][NW][64];  // 16 KiB double-buffered Q staging
    __shared__ float mbuf[NW][512];   // 16 KiB per-wave min merge
    __shared__ float red[NW];

    const int tid = threadIdx.x;
    const int k   = blockIdx.x;

    if (k < 128) {                          // obj chamfer
        int dir = k >> 6, r = k & 63;
        int b = r >> 2, rs = r & 3;
        const float* Pb = (dir ? gt_obj : pred_obj) + b*NO*3 + rs*512*3;
        const float* Qb = (dir ? pred_obj : gt_obj) + b*NO*3;
        chamfer_block<4, false>(Pb, Qb, 2 + dir, has_contact[b],
                                qsb, mbuf, red, ws);
    } else if (k < 192) {                   // repulsion
        int t = k - 128;
        int b = t >> 2, rs = t & 3;
        rep_block(pred_obj + b*NO*3 + rs*512*3, pred_obj + b*NO*3,
                  has_contact[b], qsb, red, ws);
    } else if (k < 224) {                   // hand chamfer (two 512-row passes)
        int t = k - 192;
        int dir = t >> 4, b = t & 15;
        const float* Pb = (dir ? gt_hand : pred_hand) + b*NH*3;
        const float* Qb = (dir ? pred_hand : gt_hand) + b*NH*3;
        chamfer_block<2, false>(Pb,           Qb, dir, 1.f, qsb, mbuf, red, ws);
        chamfer_block<2, false>(Pb + 512*3,   Qb, dir, 1.f, qsb, mbuf, red, ws);
    } else if (k < 256) {                   // penetration (two 512-row passes)
        int t = k - 224;
        int b = t >> 1, half = t & 1;
        const float* Pb = pred_obj + b*NO*3 + half*1024*3;
        const float* Qb = pred_hand + b*NH*3;
        float hc = has_contact[b];
        chamfer_block<2, true>(Pb,          Qb, 5, hc, qsb, mbuf, red, ws);
        chamfer_block<2, true>(Pb + 512*3,  Qb, 5, hc, qsb, mbuf, red, ws);
    } else if (k == 256) {                  // focal
        float fsum = 0.f;
        for (int i = tid; i < B*NH; i += 512) {
            float l = logits[i];
            float y = gt_contact[i];
            float bce = fmaxf(l, 0.f) - l*y + log1pf(expf(-fabsf(l)));
            float pt  = expf(-bce);
            float om  = 1.f - pt;
            fsum += ALPHA_FOCAL * om * om * bce;
        }
        float fT = block_reduce_sum(fsum, red);
        if (tid == 0) atomicAdd(&ws[6], fT);
    } else if (k == 257) {                  // qpos
        float qsum = 0.f;
        for (int i = tid; i < B*DQ; i += 512) {
            float d = pred_qpos[i] - gt_qpos[i];
            qsum += d*d;
        }
        float qT = block_reduce_sum(qsum, red);
        if (tid == 0) atomicAdd(&ws[7], qT);
    } else {                                // pose + valid
        float psum = 0.f, vsum = 0.f;
        if (tid < B) {
            const float* pp = pred_pose + tid*7;
            const float* gp = gt_pose   + tid*7;
            float lt = (fabsf(pp[0]-gp[0]) + fabsf(pp[1]-gp[1]) + fabsf(pp[2]-gp[2])) * (1.f/3.f);
            float npn = wsqrt(pp[3]*pp[3] + pp[4]*pp[4] + pp[5]*pp[5] + pp[6]*pp[6]);
            float ngn = wsqrt(gp[3]*gp[3] + gp[4]*gp[4] + gp[5]*gp[5] + gp[6]*gp[6]);
            float dot = (pp[3]*gp[3] + pp[4]*gp[4] + pp[5]*gp[5] + pp[6]*gp[6]) / (npn * ngn);
            float lr = 1.f - fabsf(dot);
            psum = (lt + 0.1f*lr) * has_contact[tid];
            vsum = has_contact[tid];
        }
        float pT = block_reduce_sum(psum, red);
        float vT = block_reduce_sum(vsum, red);
        if (tid == 0) { atomicAdd(&ws[8], pT); atomicAdd(&ws[9], vT); }
    }

    if (tid == 0) {
        __threadfence();
        unsigned* cnt = (unsigned*)(ws + 15);
        unsigned old = atomicAdd(cnt, 1u);
        if (old == 258u) {                  // last of 259 blocks finalizes
            __threadfence();
            float s0 = atomicAdd(&ws[0], 0.f), s1 = atomicAdd(&ws[1], 0.f);
            float s2 = atomicAdd(&ws[2], 0.f), s3 = atomicAdd(&ws[3], 0.f);
            float s4 = atomicAdd(&ws[4], 0.f), s5 = atomicAdd(&ws[5], 0.f);
            float s6 = atomicAdd(&ws[6], 0.f), s7 = atomicAdd(&ws[7], 0.f);
            float s8 = atomicAdd(&ws[8], 0.f), s9 = atomicAdd(&ws[9], 0.f);
            double vT    = s9;
            double valid = vT + 1e-6;
            double NOd   = (double)NO;
            // repulsion: sum relu(R-d) = hc-weighted (NO^2*R - S) minus diagonal
            double repw  = vT*NOd*NOd*(double)RADIUS_REP - (double)s4;
            double repx  = repw - vT*NOd*((double)RADIUS_REP - 1e-6);
            double loss_cd_hand = ((double)s0 + (double)s1) / (double)(B*NH);
            double loss_cd_obj  = ((double)s2 + (double)s3) / (NOd * valid);
            double loss_rep     = repx / (NOd * NOd * valid);
            double loss_pen     = (double)s5 / (NOd * valid);
            double loss_pose    = (double)s8 / valid;
            double loss_qpos    = (double)s7 / (double)(B*DQ);
            double loss_contact = (double)s6 / (double)(B*NH);
            double total = 5.0*loss_cd_hand + 5.0*loss_cd_obj + 2.0*loss_pose
                         + 1.0*loss_qpos + 2.0*loss_contact
                         + 0.5*loss_rep + 0.5*loss_pen;
            out[0] = (float)total;
        }
    }
}

extern "C" void kernel_launch(void* const* d_in, const int* in_sizes, int n_in,
                              void* d_out, int out_size, void* d_ws, size_t ws_size,
                              hipStream_t stream) {
    const float* pred_hand   = (const float*)d_in[0];
    const float* pred_obj    = (const float*)d_in[1];
    const float* pred_pose   = (const float*)d_in[2];
    const float* pred_qpos   = (const float*)d_in[3];
    const float* logits      = (const float*)d_in[4];
    const float* gt_hand     = (const float*)d_in[5];
    const float* gt_obj      = (const float*)d_in[6];
    const float* gt_pose     = (const float*)d_in[7];
    const float* gt_qpos     = (const float*)d_in[8];
    const float* gt_contact  = (const float*)d_in[9];
    const float* has_contact = (const float*)d_in[10];

    float* ws = (float*)d_ws;

    hipMemsetAsync(ws, 0, WS_SCAL * sizeof(float), stream);    // 64 B only

    loss_kernel<<<259, 512, 0, stream>>>(pred_hand, pred_obj, gt_hand, gt_obj,
                                         has_contact, logits, gt_contact,
                                         pred_qpos, gt_qpos, pred_pose, gt_pose,
                                         ws, (float*)d_out);
}